// Round 7
// baseline (237.468 us; speedup 1.0000x reference)
//
#include <hip/hip_runtime.h>

#define B_DIM 8192
#define NOUT  1024
#define KDIM  2048

typedef __bf16 bf16x8 __attribute__((ext_vector_type(8)));
typedef float  f32x4  __attribute__((ext_vector_type(4)));

__device__ __forceinline__ unsigned short f2bf(float f) {
  unsigned int u = __float_as_uint(f);
  u += 0x7fff + ((u >> 16) & 1);   // RNE
  return (unsigned short)(u >> 16);
}
__device__ __forceinline__ float sigmoid_f(float x) {
  return 1.0f / (1.0f + __expf(-x));
}
__device__ __forceinline__ float tanh_f(float x) {
  return 1.0f - 2.0f / (__expf(2.0f * x) + 1.0f);
}
__device__ __forceinline__ void gload_lds16(const void* g, void* l) {
  __builtin_amdgcn_global_load_lds(
      (const __attribute__((address_space(1))) void*)g,
      (__attribute__((address_space(3))) void*)l, 16, 0, 0);
}

// gate-interleaved weight column index (round-2/4/6 mapping)
__device__ __forceinline__ int cimap(int g, int n) {
  return ((n >> 6) << 8) | ((g >> 1) << 7) | (((n >> 4) & 3) << 5) |
         ((g & 1) << 4) | (n & 15);
}

// ---------------- kernel 1: pack xh = concat(x, out_tm1) as bf16 ------------
__global__ void pack_xh_kernel(const float* __restrict__ x,
                               const float* __restrict__ h,
                               unsigned short* __restrict__ xh) {
  const long total = (long)B_DIM * KDIM / 4;
  for (long i = (long)blockIdx.x * blockDim.x + threadIdx.x; i < total;
       i += (long)gridDim.x * blockDim.x) {
    long e = i * 4;
    int b = (int)(e >> 11);
    int c = (int)(e & 2047);
    float4 v = (c < 1024)
        ? *reinterpret_cast<const float4*>(x + (long)b * 1024 + c)
        : *reinterpret_cast<const float4*>(h + (long)b * 1024 + (c - 1024));
    ushort4 o;
    o.x = f2bf(v.x); o.y = f2bf(v.y); o.z = f2bf(v.z); o.w = f2bf(v.w);
    *reinterpret_cast<ushort4*>(xh + e) = o;
  }
}

// ------- kernel 2: wt[ci][k] = bf16(W_g[k][n]), ci = gate-interleaved -------
__global__ void transpose_w_kernel(const float* __restrict__ Wf,
                                   const float* __restrict__ Wi,
                                   const float* __restrict__ Wc,
                                   const float* __restrict__ Wo,
                                   unsigned short* __restrict__ wt) {
  __shared__ float tile[32][33];
  const int g = blockIdx.z;
  const float* W = (g == 0) ? Wf : (g == 1) ? Wi : (g == 2) ? Wc : Wo;
  const int n0 = blockIdx.x * 32;
  const int k0 = blockIdx.y * 32;
  const int tx = threadIdx.x, ty = threadIdx.y;
#pragma unroll
  for (int r = ty; r < 32; r += 8)
    tile[r][tx] = W[(long)(k0 + r) * NOUT + n0 + tx];
  __syncthreads();
#pragma unroll
  for (int r = ty; r < 32; r += 8) {
    int ci = cimap(g, n0 + r);
    wt[(long)ci * KDIM + k0 + tx] = f2bf(tile[tx][r]);
  }
}

// ---- kernel 3: 256x256x64 GEMM; A via LDS dbuf, B direct from L2 ----------
// LDS (64 KB): A(buf,half) = buf*32768 + half*16384
// Per tile t (buf = t&1), 2 phases:
//  PhA: bq0,bq1 gathers (8 global->reg); stage A0(t+1)->!buf (2 gload_lds);
//       ds_read af<-A0(buf) (8); vmcnt(10); BAR; MFMA(0,0)+(0,1)
//  PhB: stage A1(t+1)->!buf (2); ds_read af<-A1(buf) (8);
//       vmcnt(2);  BAR; MFMA(1,1)+(1,0)
// Positional vmcnt (in-order retirement, m135):
//  @PhA: outstanding oldest->newest [A1(t):2][bq:8][A0(t+1):2]=12 -> <=10
//        retires A1(t) => landed one barrier before PhB's reads.  RAW ok.
//  @PhB: after compiler's bq-readiness waits, outstanding
//        [A0(t+1):2][A1(t+1):2]=4 -> <=2 retires A0(t+1) => landed one
//        barrier before PhA(t+1)'s reads.  RAW ok.
//  A0(t)/A1(t) guarantees thus always precede (in barrier order) the phase
//  that ds_reads them.  Prologue: stage A0(0),A1(0); vmcnt(2); BAR.
// WAR: stages target !buf, last read one full tile earlier; reads are
//  consumed (lgkm) before that wave's next barrier, and stages issue only
//  after passing a later barrier. Same proof as round-6.
#define BAR()   { __builtin_amdgcn_s_barrier(); __builtin_amdgcn_sched_barrier(0); }
#define VM10()  { asm volatile("s_waitcnt vmcnt(10)" ::: "memory"); }
#define VM2()   { asm volatile("s_waitcnt vmcnt(2)" ::: "memory"); }
#define VM0()   { asm volatile("s_waitcnt vmcnt(0)" ::: "memory"); }

__device__ __forceinline__ void stage_half(const char* g, long grow0, int kt,
                                           char* ldsm, int base,
                                           int wave, int lane) {
  const int rsub = lane >> 3;
  const int scol = (((lane & 7) ^ rsub) << 4);      // pre-swizzled source col
  const long rowb = (grow0 + wave * 8 + rsub) * 4096 + (long)kt * 128 + scol;
  gload_lds16(g + rowb,               ldsm + base + wave * 1024);
  gload_lds16(g + rowb + 64L * 4096,  ldsm + base + 8192 + wave * 1024);
}

// s=1 column is colA1 = (64|ck)^csw = colA0 ^ 64 (XOR!) -- separate bases.
#define LOAD_AF(BUF, MQ)                                                    \
  _Pragma("unroll") for (int mi = 0; mi < 4; ++mi) {                        \
    af[mi][0] = *reinterpret_cast<const bf16x8*>(                           \
        baseA0 + (BUF)*32768 + (MQ)*16384 + mi*2048);                       \
    af[mi][1] = *reinterpret_cast<const bf16x8*>(                           \
        baseA1 + (BUF)*32768 + (MQ)*16384 + mi*2048);                       \
  }

// B fragments straight from global (L2-resident per XCD): 16B/lane, 16 full
// 64B lines per load -- identical fragment layout to the old LDS path.
#define LOAD_BQG(T, P0, P1, DST)                                            \
  _Pragma("unroll") for (int s = 0; s < 2; ++s) {                           \
    DST[0][s] = *reinterpret_cast<const bf16x8*>(P0 + (long)(T)*128 + s*64);\
    DST[1][s] = *reinterpret_cast<const bf16x8*>(P1 + (long)(T)*128 + s*64);\
  }

#define MFMA16(MQ, NQ, BQ)                                                  \
  _Pragma("unroll") for (int mi = 0; mi < 4; ++mi)                          \
  _Pragma("unroll") for (int ni = 0; ni < 2; ++ni)                          \
  _Pragma("unroll") for (int s = 0; s < 2; ++s)                             \
    acc[MQ][NQ][mi][ni] = __builtin_amdgcn_mfma_f32_16x16x32_bf16(          \
        af[mi][s], BQ[ni][s], acc[MQ][NQ][mi][ni], 0, 0, 0);

__global__ __launch_bounds__(512, 2)
void lstm_gemm_kernel(const unsigned short* __restrict__ xh,
                      const unsigned short* __restrict__ wt,
                      const float* __restrict__ state,
                      const float* __restrict__ bfp,
                      const float* __restrict__ bip,
                      const float* __restrict__ bcp,
                      const float* __restrict__ bop,
                      float* __restrict__ out) {
  __shared__ __attribute__((aligned(128))) char lds[65536];

  const int tid  = threadIdx.x;
  const int wave = tid >> 6;
  const int lane = tid & 63;
  const int wm = wave >> 2;     // 0..1
  const int wn = wave & 3;      // 0..3

  // XCD-aware swizzle (nwg = 512, divisible by 8): per XCD only 2 bn values
  // -> B slice per XCD = 2 MB, L2-resident.
  int wg = blockIdx.y * 16 + blockIdx.x;
  wg = (wg & 7) * 64 + (wg >> 3);
  const int  bm = wg >> 4;      // 0..31
  const int  bn = wg & 15;      // 0..15
  const long m0 = (long)bm * 256;
  const long n0 = (long)bn * 256;

  const int lrow  = lane & 15;
  const int csw   = (lane & 7) << 4;
  const int ck    = (lane >> 4) << 4;
  const int colA0 = ck ^ csw;           // swizzled byte col, k-half s=0
  const int colA1 = (64 | ck) ^ csw;    // swizzled byte col, k-half s=1

  const char* baseA0 = lds + (wm * 64 + lrow) * 128 + colA0;
  const char* baseA1 = lds + (wm * 64 + lrow) * 128 + colA1;

  const char* xh_b = (const char*)xh;  // 4096 B rows
  const char* wt_b = (const char*)wt;  // 4096 B rows

  // B gather base pointers: row ci = n0 + NQ*128 + wn*32 + ni*16 + (l&15),
  // k-byte = (l>>4)*16 (+ t*128 + s*64 in-loop).
  const char* bgbase = wt_b + (long)(n0 + wn * 32 + lrow) * 4096 + (ck);
  const char* bg00 = bgbase;                       // NQ0 ni0
  const char* bg01 = bgbase + 16L * 4096;          // NQ0 ni1
  const char* bg10 = bgbase + 128L * 4096;         // NQ1 ni0
  const char* bg11 = bgbase + 144L * 4096;         // NQ1 ni1

  // ---- prologue: stage A halves of tile 0 into buf0; retire A0(0); barrier
  stage_half(xh_b, m0,        0, lds, 0,     wave, lane); // A0(0)
  stage_half(xh_b, m0 + 128,  0, lds, 16384, wave, lane); // A1(0)

  f32x4 acc[2][2][4][2] = {};
  bf16x8 af[4][2];
  bf16x8 bq0[2][2];
  bf16x8 bq1[2][2];

  VM2();    // A0(0) landed; A1(0) still in flight (retired by VM10 @ t=0)
  BAR();

  for (int t = 0; t < 32; t += 2) {
    const int k1  = t + 1;
    const int k2c = (t + 2 > 31) ? 31 : t + 2;   // clamp: re-stage, unread

    // ================= tile t (buf0), stage (t+1)->buf1 =================
    // PhA
    LOAD_BQG(t, bg00, bg01, bq0)
    LOAD_BQG(t, bg10, bg11, bq1)
    stage_half(xh_b, m0, k1, lds, 32768, wave, lane);          // A0(t+1)
    LOAD_AF(0, 0)
    VM10(); BAR();
    __builtin_amdgcn_s_setprio(1);
    MFMA16(0, 0, bq0) MFMA16(0, 1, bq1)
    __builtin_amdgcn_s_setprio(0);
    // PhB
    stage_half(xh_b, m0 + 128, k1, lds, 32768 + 16384, wave, lane); // A1(t+1)
    LOAD_AF(0, 1)
    VM2(); BAR();
    __builtin_amdgcn_s_setprio(1);
    MFMA16(1, 1, bq1) MFMA16(1, 0, bq0)
    __builtin_amdgcn_s_setprio(0);

    // ================= tile t+1 (buf1), stage (t+2)->buf0 =================
    // PhA
    LOAD_BQG(k1, bg00, bg01, bq0)
    LOAD_BQG(k1, bg10, bg11, bq1)
    stage_half(xh_b, m0, k2c, lds, 0, wave, lane);             // A0(t+2)
    LOAD_AF(1, 0)
    VM10(); BAR();
    __builtin_amdgcn_s_setprio(1);
    MFMA16(0, 0, bq0) MFMA16(0, 1, bq1)
    __builtin_amdgcn_s_setprio(0);
    // PhB
    stage_half(xh_b, m0 + 128, k2c, lds, 16384, wave, lane);   // A1(t+2)
    LOAD_AF(1, 1)
    VM2(); BAR();
    __builtin_amdgcn_s_setprio(1);
    MFMA16(1, 1, bq1) MFMA16(1, 0, bq0)
    __builtin_amdgcn_s_setprio(0);
  }
  VM0();   // drain outstanding stages before epilogue

  // ---- fused LSTM epilogue: lane's 4 n-frags are the 4 gates of column nout
  const int   nout = bn * 64 + wn * 16 + lrow;     // 0..1023
  const int   rsub4 = (lane >> 4) << 2;
  const float bfv = bfp[nout], biv = bip[nout];
  const float bcv = bcp[nout], bov = bop[nout];
  float* out2 = out + (long)B_DIM * NOUT;
#pragma unroll
  for (int mq = 0; mq < 2; ++mq)
#pragma unroll
    for (int mi = 0; mi < 4; ++mi)
#pragma unroll
      for (int v = 0; v < 4; ++v) {
        const long row = m0 + mq * 128 + wm * 64 + mi * 16 + rsub4 + v;
        float fg = sigmoid_f(acc[mq][0][mi][0][v] + bfv);
        float ig = sigmoid_f(acc[mq][0][mi][1][v] + biv);
        float cg = tanh_f   (acc[mq][1][mi][0][v] + bcv);
        float og = sigmoid_f(acc[mq][1][mi][1][v] + bov);
        float st = state[row * NOUT + nout];
        float ns = st * fg + ig * cg;
        out [row * NOUT + nout] = og * tanh_f(ns);
        out2[row * NOUT + nout] = ns;
      }
}

extern "C" void kernel_launch(void* const* d_in, const int* in_sizes, int n_in,
                              void* d_out, int out_size, void* d_ws, size_t ws_size,
                              hipStream_t stream) {
  const float* x     = (const float*)d_in[0];
  const float* h     = (const float*)d_in[1];
  const float* state = (const float*)d_in[2];
  const float* Wf    = (const float*)d_in[3];
  const float* bfp   = (const float*)d_in[4];
  const float* Wi    = (const float*)d_in[5];
  const float* bip   = (const float*)d_in[6];
  const float* Wc    = (const float*)d_in[7];
  const float* bcp   = (const float*)d_in[8];
  const float* Wo    = (const float*)d_in[9];
  const float* bop   = (const float*)d_in[10];
  float* out = (float*)d_out;

  unsigned short* xh = (unsigned short*)d_ws;
  unsigned short* wt = (unsigned short*)((char*)d_ws + (size_t)B_DIM * KDIM * 2);

  hipLaunchKernelGGL(pack_xh_kernel, dim3(2048), dim3(256), 0, stream, x, h, xh);
  hipLaunchKernelGGL(transpose_w_kernel, dim3(NOUT / 32, KDIM / 32, 4),
                     dim3(32, 8), 0, stream, Wf, Wi, Wc, Wo, wt);
  hipLaunchKernelGGL(lstm_gemm_kernel, dim3(16, 32), dim3(512), 0, stream,
                     xh, wt, state, bfp, bip, bcp, bop, out);
}

// Round 8
// 157.915 us; speedup vs baseline: 1.5038x; 1.5038x over previous
//
#include <hip/hip_runtime.h>

#define B_DIM 8192
#define NOUT  1024
#define KDIM  2048

typedef __bf16 bf16x8 __attribute__((ext_vector_type(8)));
typedef float  f32x4  __attribute__((ext_vector_type(4)));

__device__ __forceinline__ unsigned short f2bf(float f) {
  unsigned int u = __float_as_uint(f);
  u += 0x7fff + ((u >> 16) & 1);   // RNE
  return (unsigned short)(u >> 16);
}
__device__ __forceinline__ float sigmoid_f(float x) {
  return 1.0f / (1.0f + __expf(-x));
}
__device__ __forceinline__ float tanh_f(float x) {
  return 1.0f - 2.0f / (__expf(2.0f * x) + 1.0f);
}
__device__ __forceinline__ void gload_lds16(const void* g, void* l) {
  __builtin_amdgcn_global_load_lds(
      (const __attribute__((address_space(1))) void*)g,
      (__attribute__((address_space(3))) void*)l, 16, 0, 0);
}

// gate-interleaved weight column index (round-2/4/6 mapping)
__device__ __forceinline__ int cimap(int g, int n) {
  return ((n >> 6) << 8) | ((g >> 1) << 7) | (((n >> 4) & 3) << 5) |
         ((g & 1) << 4) | (n & 15);
}

// ---------------- kernel 1: pack xh = concat(x, out_tm1) as bf16 ------------
__global__ void pack_xh_kernel(const float* __restrict__ x,
                               const float* __restrict__ h,
                               unsigned short* __restrict__ xh) {
  const long total = (long)B_DIM * KDIM / 4;
  for (long i = (long)blockIdx.x * blockDim.x + threadIdx.x; i < total;
       i += (long)gridDim.x * blockDim.x) {
    long e = i * 4;
    int b = (int)(e >> 11);
    int c = (int)(e & 2047);
    float4 v = (c < 1024)
        ? *reinterpret_cast<const float4*>(x + (long)b * 1024 + c)
        : *reinterpret_cast<const float4*>(h + (long)b * 1024 + (c - 1024));
    ushort4 o;
    o.x = f2bf(v.x); o.y = f2bf(v.y); o.z = f2bf(v.z); o.w = f2bf(v.w);
    *reinterpret_cast<ushort4*>(xh + e) = o;
  }
}

// ------- kernel 2: wt[ci][k] = bf16(W_g[k][n]), ci = gate-interleaved -------
__global__ void transpose_w_kernel(const float* __restrict__ Wf,
                                   const float* __restrict__ Wi,
                                   const float* __restrict__ Wc,
                                   const float* __restrict__ Wo,
                                   unsigned short* __restrict__ wt) {
  __shared__ float tile[32][33];
  const int g = blockIdx.z;
  const float* W = (g == 0) ? Wf : (g == 1) ? Wi : (g == 2) ? Wc : Wo;
  const int n0 = blockIdx.x * 32;
  const int k0 = blockIdx.y * 32;
  const int tx = threadIdx.x, ty = threadIdx.y;
#pragma unroll
  for (int r = ty; r < 32; r += 8)
    tile[r][tx] = W[(long)(k0 + r) * NOUT + n0 + tx];
  __syncthreads();
#pragma unroll
  for (int r = ty; r < 32; r += 8) {
    int ci = cimap(g, n0 + r);
    wt[(long)ci * KDIM + k0 + tx] = f2bf(tile[tx][r]);
  }
}

// --- kernel 3: 256x256x64 GEMM, m201-style 8-phase schedule + fused LSTM ---
// LDS map (bytes): A(buf,half) = buf*32768 + half*16384
//                  B(buf,half) = 65536 + buf*32768 + half*16384
// Per K-tile t (buf = t&1), 4 phases, each: { ds_reads; stage 1 half;
//   [P1: lgkmcnt(8)] [P4: vmcnt(6)]; BAR; (compiler lgkm); setprio;
//   16 MFMA; setprio; BAR }
// Stage order:  P1: A1(t+1)->!buf   P2: A0(t+2)->buf
//               P3: B0(t+2)->buf    P4: B1(t+2)->buf
// Read order:   P1: A0(t),B0(t)     P2: B1(t)   P3: A1(t)   P4: none
// RAW (single vmcnt(6) @ P4): outstanding there = stages of (t,P2..P4)=6
//   -> retires everything <= (t,P1) = A1(t+1) plus A0/B0/B1(t+1) staged at
//   (t-1,P2..P4). So ALL 4 halves of tile t+1 are visible entering it.
// WAR: each restaged slot's last read is >=1 closing-barrier earlier:
//   A0(buf) read (t,P1) -> restaged (t,P2); B0 read (t,P1) -> (t,P3);
//   B1 read (t,P2) -> (t,P4); A1(!buf) read (t-1,P3) -> (t,P1).
// Tail: clamped re-stages write only already-consumed slots.
#define BAR()   { __builtin_amdgcn_s_barrier(); __builtin_amdgcn_sched_barrier(0); }
#define LGKM8() { asm volatile("s_waitcnt lgkmcnt(8)" ::: "memory"); }
#define VM6()   { asm volatile("s_waitcnt vmcnt(6)" ::: "memory"); }
#define VM0()   { asm volatile("s_waitcnt vmcnt(0)" ::: "memory"); }

__device__ __forceinline__ void stage_half(const char* g, long grow0, int kt,
                                           char* ldsm, int base,
                                           int wave, int lane) {
  const int rsub = lane >> 3;
  const int scol = (((lane & 7) ^ rsub) << 4);      // pre-swizzled source col
  const long rowb = (grow0 + wave * 8 + rsub) * 4096 + (long)kt * 128 + scol;
  gload_lds16(g + rowb,               ldsm + base + wave * 1024);
  gload_lds16(g + rowb + 64L * 4096,  ldsm + base + 8192 + wave * 1024);
}

// s=1 column is colA1 = (64|ck)^csw = colA0 ^ 64 (XOR!) -- separate bases.
#define LOAD_AF(BUF, MQ)                                                    \
  _Pragma("unroll") for (int mi = 0; mi < 4; ++mi) {                        \
    af[mi][0] = *reinterpret_cast<const bf16x8*>(                           \
        baseA0 + (BUF)*32768 + (MQ)*16384 + mi*2048);                       \
    af[mi][1] = *reinterpret_cast<const bf16x8*>(                           \
        baseA1 + (BUF)*32768 + (MQ)*16384 + mi*2048);                       \
  }

#define LOAD_BQ(BUF, NQ, DST)                                               \
  _Pragma("unroll") for (int ni = 0; ni < 2; ++ni) {                        \
    DST[ni][0] = *reinterpret_cast<const bf16x8*>(                          \
        baseB0 + (BUF)*32768 + (NQ)*16384 + ni*2048);                       \
    DST[ni][1] = *reinterpret_cast<const bf16x8*>(                          \
        baseB1 + (BUF)*32768 + (NQ)*16384 + ni*2048);                       \
  }

#define MFMA16(MQ, NQ, BQ)                                                  \
  __builtin_amdgcn_s_setprio(1);                                            \
  _Pragma("unroll") for (int mi = 0; mi < 4; ++mi)                          \
  _Pragma("unroll") for (int ni = 0; ni < 2; ++ni)                          \
  _Pragma("unroll") for (int s = 0; s < 2; ++s)                             \
    acc[MQ][NQ][mi][ni] = __builtin_amdgcn_mfma_f32_16x16x32_bf16(          \
        af[mi][s], BQ[ni][s], acc[MQ][NQ][mi][ni], 0, 0, 0);                \
  __builtin_amdgcn_s_setprio(0);

// One K-tile = 4 phases (m201 form: 2 barriers/phase, vmcnt only at P4).
#define KTILE(BUF, KA1, KN)                                                 \
  /* P1 */                                                                  \
  LOAD_AF(BUF, 0) LOAD_BQ(BUF, 0, bq0)                                      \
  stage_half(xh_b, m0 + 128, (KA1), lds, (1-(BUF))*32768 + 16384, wave, lane);\
  LGKM8(); BAR();                                                           \
  MFMA16(0, 0, bq0) BAR();                                                  \
  /* P2 */                                                                  \
  LOAD_BQ(BUF, 1, bq1)                                                      \
  stage_half(xh_b, m0, (KN), lds, (BUF)*32768, wave, lane);                 \
  BAR();                                                                    \
  MFMA16(0, 1, bq1) BAR();                                                  \
  /* P3 */                                                                  \
  LOAD_AF(BUF, 1)                                                           \
  stage_half(wt_b, n0, (KN), lds, 65536 + (BUF)*32768, wave, lane);         \
  BAR();                                                                    \
  MFMA16(1, 1, bq1) BAR();                                                  \
  /* P4 */                                                                  \
  stage_half(wt_b, n0 + 128, (KN), lds, 65536 + (BUF)*32768 + 16384, wave, lane);\
  VM6(); BAR();                                                             \
  MFMA16(1, 0, bq0) BAR();

__global__ __launch_bounds__(512, 2)
void lstm_gemm_kernel(const unsigned short* __restrict__ xh,
                      const unsigned short* __restrict__ wt,
                      const float* __restrict__ state,
                      const float* __restrict__ bfp,
                      const float* __restrict__ bip,
                      const float* __restrict__ bcp,
                      const float* __restrict__ bop,
                      float* __restrict__ out) {
  __shared__ __attribute__((aligned(128))) char lds[131072];

  const int tid  = threadIdx.x;
  const int wave = tid >> 6;
  const int lane = tid & 63;
  const int wm = wave >> 2;     // 0..1
  const int wn = wave & 3;      // 0..3

  // XCD-aware swizzle (nwg = 512, divisible by 8)
  int wg = blockIdx.y * 16 + blockIdx.x;
  wg = (wg & 7) * 64 + (wg >> 3);
  const int  bm = wg >> 4;      // 0..31
  const int  bn = wg & 15;      // 0..15
  const long m0 = (long)bm * 256;
  const long n0 = (long)bn * 256;

  const int lrow  = lane & 15;
  const int csw   = (lane & 7) << 4;
  const int ck    = (lane >> 4) << 4;
  const int colA0 = ck ^ csw;           // swizzled byte col, k-half s=0
  const int colA1 = (64 | ck) ^ csw;    // swizzled byte col, k-half s=1

  const char* baseA0 = lds + (wm * 64 + lrow) * 128 + colA0;
  const char* baseA1 = lds + (wm * 64 + lrow) * 128 + colA1;
  const char* baseB0 = lds + 65536 + (wn * 32 + lrow) * 128 + colA0;
  const char* baseB1 = lds + 65536 + (wn * 32 + lrow) * 128 + colA1;

  const char* xh_b = (const char*)xh;  // 4096 B rows
  const char* wt_b = (const char*)wt;  // 4096 B rows

  // ---- prologue: tile0 all 4 halves + tile1 {A0,B0,B1}; vmcnt(6); barrier
  stage_half(xh_b, m0,        0, lds, 0,             wave, lane); // A0(0)
  stage_half(wt_b, n0,        0, lds, 65536,         wave, lane); // B0(0)
  stage_half(wt_b, n0 + 128,  0, lds, 65536 + 16384, wave, lane); // B1(0)
  stage_half(xh_b, m0 + 128,  0, lds, 16384,         wave, lane); // A1(0)
  stage_half(xh_b, m0,        1, lds, 32768,                 wave, lane); // A0(1)
  stage_half(wt_b, n0,        1, lds, 65536 + 32768,         wave, lane); // B0(1)
  stage_half(wt_b, n0 + 128,  1, lds, 65536 + 32768 + 16384, wave, lane); // B1(1)

  f32x4 acc[2][2][4][2] = {};
  bf16x8 af[4][2];
  bf16x8 bq0[2][2];
  bf16x8 bq1[2][2];

  VM6();    // retires tile0's 4 halves (14 issued -> 6 outstanding)
  BAR();

  for (int t = 0; t < 32; t += 2) {
    const int k2c = (t + 2 > 31) ? 31 : t + 2;   // clamp: re-stage, unread
    const int k3c = (t + 3 > 31) ? 31 : t + 3;
    // tile t   (buf0): stage A1(t+1)->buf1; A0,B0,B1(t+2)->buf0
    KTILE(0, t + 1, k2c)
    // tile t+1 (buf1): stage A1(t+2)->buf0; A0,B0,B1(t+3)->buf1
    KTILE(1, k2c, k3c)
  }
  VM0();   // drain outstanding stages before epilogue

  // ---- fused LSTM epilogue: lane's 4 n-frags are the 4 gates of column nout
  const int   nout = bn * 64 + wn * 16 + lrow;     // 0..1023
  const int   rsub4 = (lane >> 4) << 2;
  const float bfv = bfp[nout], biv = bip[nout];
  const float bcv = bcp[nout], bov = bop[nout];
  float* out2 = out + (long)B_DIM * NOUT;
#pragma unroll
  for (int mq = 0; mq < 2; ++mq)
#pragma unroll
    for (int mi = 0; mi < 4; ++mi)
#pragma unroll
      for (int v = 0; v < 4; ++v) {
        const long row = m0 + mq * 128 + wm * 64 + mi * 16 + rsub4 + v;
        float fg = sigmoid_f(acc[mq][0][mi][0][v] + bfv);
        float ig = sigmoid_f(acc[mq][0][mi][1][v] + biv);
        float cg = tanh_f   (acc[mq][1][mi][0][v] + bcv);
        float og = sigmoid_f(acc[mq][1][mi][1][v] + bov);
        float st = state[row * NOUT + nout];
        float ns = st * fg + ig * cg;
        out [row * NOUT + nout] = og * tanh_f(ns);
        out2[row * NOUT + nout] = ns;
      }
}

extern "C" void kernel_launch(void* const* d_in, const int* in_sizes, int n_in,
                              void* d_out, int out_size, void* d_ws, size_t ws_size,
                              hipStream_t stream) {
  const float* x     = (const float*)d_in[0];
  const float* h     = (const float*)d_in[1];
  const float* state = (const float*)d_in[2];
  const float* Wf    = (const float*)d_in[3];
  const float* bfp   = (const float*)d_in[4];
  const float* Wi    = (const float*)d_in[5];
  const float* bip   = (const float*)d_in[6];
  const float* Wc    = (const float*)d_in[7];
  const float* bcp   = (const float*)d_in[8];
  const float* Wo    = (const float*)d_in[9];
  const float* bop   = (const float*)d_in[10];
  float* out = (float*)d_out;

  unsigned short* xh = (unsigned short*)d_ws;
  unsigned short* wt = (unsigned short*)((char*)d_ws + (size_t)B_DIM * KDIM * 2);

  hipLaunchKernelGGL(pack_xh_kernel, dim3(2048), dim3(256), 0, stream, x, h, xh);
  hipLaunchKernelGGL(transpose_w_kernel, dim3(NOUT / 32, KDIM / 32, 4),
                     dim3(32, 8), 0, stream, Wf, Wi, Wc, Wo, wt);
  hipLaunchKernelGGL(lstm_gemm_kernel, dim3(16, 32), dim3(512), 0, stream,
                     xh, wt, state, bfp, bip, bcp, bop, out);
}